// Round 5
// baseline (179.849 us; speedup 1.0000x reference)
//
#include <hip/hip_runtime.h>
#include <hip/hip_bf16.h>
#include <math.h>

// Problem constants
#define BROWS 16384
#define IN_DIM 128
#define HID 512
#define ATT 256
#define KTOT 896          // IN_DIM + HID + ATT
#define KC_TOT 112        // KTOT / 8

typedef __bf16 bf16x8 __attribute__((ext_vector_type(8)));
typedef float f32x4 __attribute__((ext_vector_type(4)));

// ---------------------------------------------------------------------------
// Kernel 1: pack augmented weights -> B_stage[jt(8)][kc(112)][nl(192)][8] bf16.
// nl = jg*48 + type*16 + j16 ; jg in [0,4), type 0=gate 1=dyn 2=tau.
// j = jt*64 + jg*16 + j16. tau rows ZERO outside k in [128,640).
// ---------------------------------------------------------------------------
__device__ __forceinline__ float softplus_f(float x) {
    return fmaxf(x, 0.0f) + log1pf(__expf(-fabsf(x)));
}

__global__ void pack_B(const float* __restrict__ W_gd, const float* __restrict__ W_tau,
                       const float* __restrict__ gleak, const float* __restrict__ cm,
                       __hip_bfloat16* __restrict__ B_stage, float* __restrict__ dconst) {
    const int cid = blockIdx.x * 256 + threadIdx.x;   // 672*256 = 172032 = 8*112*192
    if (cid < HID) {
        dconst[cid] = softplus_f(cm[cid]) + softplus_f(gleak[cid]) + 1e-6f;
    }
    const int nl = cid % 192;
    const int kc = (cid / 192) % KC_TOT;
    const int jt = cid / (192 * KC_TOT);
    const int jg = nl / 48, type = (nl % 48) / 16, j16 = nl % 16;
    const int j = jt * 64 + jg * 16 + j16;
    const int k0 = kc * 8;

    float v[8];
    if (type == 0) {
        const float* s = W_gd + (size_t)j * KTOT + k0;
        #pragma unroll
        for (int i = 0; i < 8; ++i) v[i] = s[i];
    } else if (type == 1) {
        const float* s = W_gd + (size_t)(HID + j) * KTOT + k0;
        #pragma unroll
        for (int i = 0; i < 8; ++i) v[i] = s[i];
    } else {
        if (k0 >= IN_DIM && k0 < IN_DIM + HID) {
            const float* s = W_tau + (size_t)j * HID + (k0 - IN_DIM);
            #pragma unroll
            for (int i = 0; i < 8; ++i) v[i] = s[i];
        } else {
            #pragma unroll
            for (int i = 0; i < 8; ++i) v[i] = 0.0f;
        }
    }
    union { __hip_bfloat16 hh[8]; uint4 u; } p;
    #pragma unroll
    for (int i = 0; i < 8; ++i) p.hh[i] = __float2bfloat16(v[i]);
    *(uint4*)(B_stage + (size_t)cid * 8) = p.u;
}

// ---------------------------------------------------------------------------
// Kernel 2: BARRIER-FREE deep-pipeline GEMM — R5: fix the register budget.
// Empirical launch-bounds law on this toolchain (R0/R1/R2/R4 VGPR_Count):
//   (512,4) -> 64-reg budget (SPILLS the deep-ring body: WRITE 78MB, FETCH 99MB)
//   (512,2) -> 128-reg budget (R2: 120 regs, zero spill)
// So this is the R3/R4 kernel with ONE change: __launch_bounds__(512, 2).
// Occupancy is then set by LDS: 56KB -> 2 blocks/CU = 16 waves/CU = 4 waves/
// SIMD (VGPR cap 128 @ 4 waves/SIMD agrees). This finally composes R0's TLP
// (4 waves/SIMD) with R2's per-wave efficiency (deep rings, ~120 regs):
//   A (LDS) ring-4 @ distance 2, B (L2) ring-4 @ distance 3.
// Floors: MFMA 15.5us, HBM ~16us, B-L2 traffic 1.18GB ~ 34us at ceiling.
// Prediction: ~38-48us, VGPR ~120, WRITE back to 32.7MB, FETCH ~53MB.
// ---------------------------------------------------------------------------
__global__ __launch_bounds__(512, 2) void ltc_gemm(
    const float* __restrict__ x, const float* __restrict__ h_ltc,
    const float* __restrict__ ctx, const __hip_bfloat16* __restrict__ B_stage,
    const float* __restrict__ b_gd, const float* __restrict__ b_tau,
    const float* __restrict__ dconst, float* __restrict__ out) {

    __shared__ __attribute__((aligned(16))) char As[57344];  // [kc 112][mi 32] 16B

    const int mt = blockIdx.x;          // 0..511 : rows mt*32 .. mt*32+31
    const int tid = threadIdx.x;
    const int wave = tid >> 6, lane = tid & 63;
    const int q = lane >> 4, t = lane & 15;

    // ---- Stage A (fp32 -> bf16) once. thread (mi, kcg) stages 7 chunks. ----
    const int mi = tid >> 4;            // 0..31
    const int kcg = tid & 15;           // 0..15
    #pragma unroll
    for (int s = 0; s < 7; ++s) {
        const int kc = kcg + 16 * s;
        const float* src; int rs, col;
        if (s == 0)      { src = x;     rs = IN_DIM; col = kcg * 8; }
        else if (s < 5)  { src = h_ltc; rs = HID;    col = kcg * 8 + (s - 1) * 128; }
        else             { src = ctx;   rs = ATT;    col = kcg * 8 + (s - 5) * 128; }
        const float* p = src + (size_t)(mt * 32 + mi) * rs + col;
        float4 v0 = *(const float4*)p;
        float4 v1 = *(const float4*)(p + 4);
        union { __hip_bfloat16 hh[8]; uint4 u; } pk;
        pk.hh[0] = __float2bfloat16(v0.x); pk.hh[1] = __float2bfloat16(v0.y);
        pk.hh[2] = __float2bfloat16(v0.z); pk.hh[3] = __float2bfloat16(v0.w);
        pk.hh[4] = __float2bfloat16(v1.x); pk.hh[5] = __float2bfloat16(v1.y);
        pk.hh[6] = __float2bfloat16(v1.z); pk.hh[7] = __float2bfloat16(v1.w);
        *(uint4*)(As + ((kc * 32 + (mi ^ (kc & 31))) << 4)) = pk.u;
    }
    __syncthreads();   // the ONLY barrier in this kernel

    // ---- j-loop: 4 iters x (8 waves x 16 j) covers all 512 j ----
    for (int it = 0; it < 4; ++it) {
        const int jglob = it * 128 + wave * 16;       // this wave's j base
        const int jt = jglob >> 6;                    // 0..7
        const int jg = (jglob >> 4) & 3;              // 0..3
        const __hip_bfloat16* bBase = B_stage
            + ((size_t)jt * (KC_TOT * 192) + jg * 48 + t) * 8;

        f32x4 acc[2][3];
        #pragma unroll
        for (int f = 0; f < 2; ++f)
            #pragma unroll
            for (int ty = 0; ty < 3; ++ty) acc[f][ty] = (f32x4)0.0f;

        // deep register pipelines (no barriers, no spills):
        // ab ring-4 @ distance 2 (LDS), bb ring-4 @ distance 3 (L2)
        bf16x8 ab[4][2]; bf16x8 bb[4][3];

        // prologue: A for steps 0,1 ; B for steps 0,1,2 (tau starts at step 4)
        #pragma unroll
        for (int p = 0; p < 2; ++p) {
            const int kc = p * 4 + q;
            const int sw = kc & 31;
            ab[p][0] = *(const bf16x8*)(As + ((kc * 32 + (t ^ sw)) << 4));
            ab[p][1] = *(const bf16x8*)(As + ((kc * 32 + ((16 + t) ^ sw)) << 4));
        }
        #pragma unroll
        for (int p = 0; p < 3; ++p) {
            const __hip_bfloat16* bp = bBase + (size_t)(p * 4 + q) * 1536;
            bb[p][0] = *(const bf16x8*)(bp);
            bb[p][1] = *(const bf16x8*)(bp + 128);
        }

        #pragma unroll 4
        for (int kst = 0; kst < 28; ++kst) {
            const int ca = kst & 3;
            // issue next loads first — they retire while we MFMA
            if (kst < 26) {            // A prefetch, distance 2
                const int kc = (kst + 2) * 4 + q;
                const int sw = kc & 31;
                const int na = (kst + 2) & 3;
                ab[na][0] = *(const bf16x8*)(As + ((kc * 32 + (t ^ sw)) << 4));
                ab[na][1] = *(const bf16x8*)(As + ((kc * 32 + ((16 + t) ^ sw)) << 4));
            }
            if (kst < 25) {            // B prefetch, distance 3
                const int kc = (kst + 3) * 4 + q;
                const int nbf = (kst + 3) & 3;
                const __hip_bfloat16* bp = bBase + (size_t)kc * 1536;
                bb[nbf][0] = *(const bf16x8*)(bp);
                bb[nbf][1] = *(const bf16x8*)(bp + 128);
                if (kst + 3 >= 4 && kst + 3 < 20)
                    bb[nbf][2] = *(const bf16x8*)(bp + 256);
            }
            const bool tau_cur = (kst >= 4 && kst < 20);   // k in [128,640)
            acc[0][0] = __builtin_amdgcn_mfma_f32_16x16x32_bf16(ab[ca][0], bb[ca][0], acc[0][0], 0, 0, 0);
            acc[1][0] = __builtin_amdgcn_mfma_f32_16x16x32_bf16(ab[ca][1], bb[ca][0], acc[1][0], 0, 0, 0);
            acc[0][1] = __builtin_amdgcn_mfma_f32_16x16x32_bf16(ab[ca][0], bb[ca][1], acc[0][1], 0, 0, 0);
            acc[1][1] = __builtin_amdgcn_mfma_f32_16x16x32_bf16(ab[ca][1], bb[ca][1], acc[1][1], 0, 0, 0);
            if (tau_cur) {
                acc[0][2] = __builtin_amdgcn_mfma_f32_16x16x32_bf16(ab[ca][0], bb[ca][2], acc[0][2], 0, 0, 0);
                acc[1][2] = __builtin_amdgcn_mfma_f32_16x16x32_bf16(ab[ca][1], bb[ca][2], acc[1][2], 0, 0, 0);
            }
        }

        // ---- epilogue for this wave's 32 rows x 16 j ----
        const int j = jglob + t;
        const float bgj = b_gd[j];
        const float bdj = b_gd[HID + j];
        const float btj = b_tau[j];
        const float dcj = dconst[j];
        #pragma unroll
        for (int f = 0; f < 2; ++f) {
            #pragma unroll
            for (int r = 0; r < 4; ++r) {
                const int row = mt * 32 + f * 16 + q * 4 + r;
                const float gv = acc[f][0][r] + bgj;
                const float dv = acc[f][1][r] + bdj;
                const float tp = acc[f][2][r] + btj;
                const float hv = h_ltc[(size_t)row * HID + j];
                const float sig = __builtin_amdgcn_rcpf(1.0f + __expf(-gv));
                const float th  = 1.0f - 2.0f * __builtin_amdgcn_rcpf(__expf(2.0f * dv) + 1.0f);
                const float tau = fmaxf(tp, 0.0f) + __logf(1.0f + __expf(-fabsf(tp)));
                out[(size_t)row * HID + j] = (sig * th - hv) * __builtin_amdgcn_rcpf(tau + dcj);
            }
        }
    }
}

// ---------------------------------------------------------------------------
extern "C" void kernel_launch(void* const* d_in, const int* in_sizes, int n_in,
                              void* d_out, int out_size, void* d_ws, size_t ws_size,
                              hipStream_t stream) {
    // setup_inputs order: t, h_ltc, x_t, context, W_gd, b_gd, W_tau, b_tau, gleak, cm
    const float* h_ltc = (const float*)d_in[1];
    const float* x_t   = (const float*)d_in[2];
    const float* ctx   = (const float*)d_in[3];
    const float* W_gd  = (const float*)d_in[4];
    const float* b_gd  = (const float*)d_in[5];
    const float* W_tau = (const float*)d_in[6];
    const float* b_tau = (const float*)d_in[7];
    const float* gleak = (const float*)d_in[8];
    const float* cm    = (const float*)d_in[9];

    char* ws = (char*)d_ws;
    __hip_bfloat16* B_stage = (__hip_bfloat16*)ws;      // 8*112*192*8*2 = 2,752,512 B
    float* dconst = (float*)(ws + 2752512);             // 2,048 B

    pack_B<<<672, 256, 0, stream>>>(W_gd, W_tau, gleak, cm, B_stage, dconst);
    ltc_gemm<<<512, 512, 0, stream>>>(x_t, h_ltc, ctx, B_stage, b_gd, b_tau, dconst,
                                      (float*)d_out);
}

// Round 6
// 161.676 us; speedup vs baseline: 1.1124x; 1.1124x over previous
//
#include <hip/hip_runtime.h>
#include <hip/hip_bf16.h>
#include <math.h>

// Problem constants
#define BROWS 16384
#define IN_DIM 128
#define HID 512
#define ATT 256
#define KTOT 896          // IN_DIM + HID + ATT
#define KC_TOT 112        // KTOT / 8

typedef __bf16 bf16x8 __attribute__((ext_vector_type(8)));
typedef float f32x4 __attribute__((ext_vector_type(4)));

// ---------------------------------------------------------------------------
// Kernel 1: pack augmented weights -> B_stage[jt(8)][kc(112)][nl(192)][8] bf16.
// nl = jg*48 + type*16 + j16 ; jg in [0,4), type 0=gate 1=dyn 2=tau.
// j = jt*64 + jg*16 + j16. tau rows ZERO outside k in [128,640).
// ---------------------------------------------------------------------------
__device__ __forceinline__ float softplus_f(float x) {
    return fmaxf(x, 0.0f) + log1pf(__expf(-fabsf(x)));
}

__global__ void pack_B(const float* __restrict__ W_gd, const float* __restrict__ W_tau,
                       const float* __restrict__ gleak, const float* __restrict__ cm,
                       __hip_bfloat16* __restrict__ B_stage, float* __restrict__ dconst) {
    const int cid = blockIdx.x * 256 + threadIdx.x;   // 672*256 = 172032 = 8*112*192
    if (cid < HID) {
        dconst[cid] = softplus_f(cm[cid]) + softplus_f(gleak[cid]) + 1e-6f;
    }
    const int nl = cid % 192;
    const int kc = (cid / 192) % KC_TOT;
    const int jt = cid / (192 * KC_TOT);
    const int jg = nl / 48, type = (nl % 48) / 16, j16 = nl % 16;
    const int j = jt * 64 + jg * 16 + j16;
    const int k0 = kc * 8;

    float v[8];
    if (type == 0) {
        const float* s = W_gd + (size_t)j * KTOT + k0;
        #pragma unroll
        for (int i = 0; i < 8; ++i) v[i] = s[i];
    } else if (type == 1) {
        const float* s = W_gd + (size_t)(HID + j) * KTOT + k0;
        #pragma unroll
        for (int i = 0; i < 8; ++i) v[i] = s[i];
    } else {
        if (k0 >= IN_DIM && k0 < IN_DIM + HID) {
            const float* s = W_tau + (size_t)j * HID + (k0 - IN_DIM);
            #pragma unroll
            for (int i = 0; i < 8; ++i) v[i] = s[i];
        } else {
            #pragma unroll
            for (int i = 0; i < 8; ++i) v[i] = 0.0f;
        }
    }
    union { __hip_bfloat16 hh[8]; uint4 u; } p;
    #pragma unroll
    for (int i = 0; i < 8; ++i) p.hh[i] = __float2bfloat16(v[i]);
    *(uint4*)(B_stage + (size_t)cid * 8) = p.u;
}

// ---------------------------------------------------------------------------
// Kernel 2: BARRIER-FREE GEMM — R6: buy latency tolerance with MFMA BURST
// LENGTH, not prefetch distance.
// Model (R0-R5 evidence): B L2 traffic = (16384/BM)*2.36MB. BM=32 -> 1.21GB
// -> L2-bound ~50-70us (=R0's 68). BM=64 halves traffic but R2 was latency-
// bound: compiler compresses any source-level ring to ~distance-1 (VGPR 84/120
// across R2/R5 regardless of declared depth), so per-kstep cover = MFMA burst.
// Fix: wave = 64 rows x 32 j (was x16). Per kstep: ~20 independent MFMAs
// ~= 400 SIMD-cyc burst vs ~5KB B loads -> distance-1 suffices. Per-gen
// (8 waves/CU): MFMA 800cyc (binding) > L2 714cyc > LDS ~300cyc.
// Core ~19us MFMA-bound + stage ~9.5us + epilogue ~10us => ~38-48us.
// Regs: acc[2][4][3]=96 + ab[2][4]=32 + bb[2][6]=48 + misc ~= 200 < 256 cap
// of (512,2) (allocator proven clean there: R2=120, R5=84, no spill).
// LDS 112KB, 1 block/CU, 2 waves/SIMD — BY DESIGN (MFMA-bound, not TLP-bound).
// ---------------------------------------------------------------------------
__global__ __launch_bounds__(512, 2) void ltc_gemm(
    const float* __restrict__ x, const float* __restrict__ h_ltc,
    const float* __restrict__ ctx, const __hip_bfloat16* __restrict__ B_stage,
    const float* __restrict__ b_gd, const float* __restrict__ b_tau,
    const float* __restrict__ dconst, float* __restrict__ out) {

    __shared__ __attribute__((aligned(16))) char As[114688];  // [kc 112][mi 64] 16B

    const int mt = blockIdx.x;          // 0..255 : rows mt*64 .. mt*64+63
    const int tid = threadIdx.x;
    const int wave = tid >> 6, lane = tid & 63;
    const int q = lane >> 4, t = lane & 15;

    // ---- Stage A (fp32 -> bf16) once. thread (mi0,kcg) stages 2 halves x 7. ----
    const int mi0 = tid >> 4;           // 0..31
    const int kcg = tid & 15;           // 0..15
    #pragma unroll
    for (int h = 0; h < 2; ++h) {
        const int mi = mi0 + 32 * h;
        #pragma unroll
        for (int s = 0; s < 7; ++s) {
            const int kc = kcg + 16 * s;
            const float* src; int rs, col;
            if (s == 0)      { src = x;     rs = IN_DIM; col = kcg * 8; }
            else if (s < 5)  { src = h_ltc; rs = HID;    col = kcg * 8 + (s - 1) * 128; }
            else             { src = ctx;   rs = ATT;    col = kcg * 8 + (s - 5) * 128; }
            const float* p = src + (size_t)(mt * 64 + mi) * rs + col;
            float4 v0 = *(const float4*)p;
            float4 v1 = *(const float4*)(p + 4);
            union { __hip_bfloat16 hh[8]; uint4 u; } pk;
            pk.hh[0] = __float2bfloat16(v0.x); pk.hh[1] = __float2bfloat16(v0.y);
            pk.hh[2] = __float2bfloat16(v0.z); pk.hh[3] = __float2bfloat16(v0.w);
            pk.hh[4] = __float2bfloat16(v1.x); pk.hh[5] = __float2bfloat16(v1.y);
            pk.hh[6] = __float2bfloat16(v1.z); pk.hh[7] = __float2bfloat16(v1.w);
            *(uint4*)(As + ((kc * 64 + (mi ^ (kc & 31))) << 4)) = pk.u;
        }
    }
    __syncthreads();   // the ONLY barrier in this kernel

    // ---- j-loop: 2 iters x (8 waves x 32 j) covers all 512 j ----
    for (int it = 0; it < 2; ++it) {
        const int jglob = it * 256 + wave * 32;       // this wave's j base (32 wide)
        const int jt = jglob >> 6;                    // 0..7
        const int jg = (jglob >> 4) & 3;              // 0 or 2
        const __hip_bfloat16* bBase = B_stage
            + ((size_t)jt * (KC_TOT * 192) + jg * 48 + t) * 8;
        // frag offsets (bf16 elems) within a kc row:
        //   gate jf0: +0    dyn jf0: +128   tau jf0: +256
        //   gate jf1: +384  dyn jf1: +512   tau jf1: +640

        f32x4 acc[2][4][3];   // [jf][rowfrag][type] = 96 VGPRs
        #pragma unroll
        for (int jf = 0; jf < 2; ++jf)
            #pragma unroll
            for (int f = 0; f < 4; ++f)
                #pragma unroll
                for (int ty = 0; ty < 3; ++ty) acc[jf][f][ty] = (f32x4)0.0f;

        // one-step double buffers — per-kstep MFMA burst (~400 SIMD-cyc)
        // is the latency cover; depth-1 is intentional.
        bf16x8 ab[2][4]; bf16x8 bb[2][6];

        // prologue: kstep 0 (kc = q; no tau at kst 0)
        {
            const int kc = q;
            const int sw = kc & 31;
            ab[0][0] = *(const bf16x8*)(As + ((kc * 64 + (t ^ sw)) << 4));
            ab[0][1] = *(const bf16x8*)(As + ((kc * 64 + ((16 + t) ^ sw)) << 4));
            ab[0][2] = *(const bf16x8*)(As + ((kc * 64 + ((32 + t) ^ sw)) << 4));
            ab[0][3] = *(const bf16x8*)(As + ((kc * 64 + ((48 + t) ^ sw)) << 4));
            const __hip_bfloat16* bp = bBase + (size_t)kc * 1536;
            bb[0][0] = *(const bf16x8*)(bp);
            bb[0][1] = *(const bf16x8*)(bp + 128);
            bb[0][2] = *(const bf16x8*)(bp + 384);
            bb[0][3] = *(const bf16x8*)(bp + 512);
        }

        #pragma unroll 4
        for (int kst = 0; kst < 28; ++kst) {
            const int cb = kst & 1, nb = cb ^ 1;
            // issue next step's loads first — they retire while we MFMA
            if (kst < 27) {
                const int kc = (kst + 1) * 4 + q;
                const int sw = kc & 31;
                ab[nb][0] = *(const bf16x8*)(As + ((kc * 64 + (t ^ sw)) << 4));
                ab[nb][1] = *(const bf16x8*)(As + ((kc * 64 + ((16 + t) ^ sw)) << 4));
                ab[nb][2] = *(const bf16x8*)(As + ((kc * 64 + ((32 + t) ^ sw)) << 4));
                ab[nb][3] = *(const bf16x8*)(As + ((kc * 64 + ((48 + t) ^ sw)) << 4));
                const __hip_bfloat16* bp = bBase + (size_t)kc * 1536;
                bb[nb][0] = *(const bf16x8*)(bp);
                bb[nb][1] = *(const bf16x8*)(bp + 128);
                bb[nb][2] = *(const bf16x8*)(bp + 384);
                bb[nb][3] = *(const bf16x8*)(bp + 512);
                if (kst + 1 >= 4 && kst + 1 < 20) {
                    bb[nb][4] = *(const bf16x8*)(bp + 256);
                    bb[nb][5] = *(const bf16x8*)(bp + 640);
                }
            }
            const bool tau_cur = (kst >= 4 && kst < 20);   // k in [128,640)
            #pragma unroll
            for (int f = 0; f < 4; ++f) {
                acc[0][f][0] = __builtin_amdgcn_mfma_f32_16x16x32_bf16(ab[cb][f], bb[cb][0], acc[0][f][0], 0, 0, 0);
                acc[1][f][0] = __builtin_amdgcn_mfma_f32_16x16x32_bf16(ab[cb][f], bb[cb][2], acc[1][f][0], 0, 0, 0);
                acc[0][f][1] = __builtin_amdgcn_mfma_f32_16x16x32_bf16(ab[cb][f], bb[cb][1], acc[0][f][1], 0, 0, 0);
                acc[1][f][1] = __builtin_amdgcn_mfma_f32_16x16x32_bf16(ab[cb][f], bb[cb][3], acc[1][f][1], 0, 0, 0);
            }
            if (tau_cur) {
                #pragma unroll
                for (int f = 0; f < 4; ++f) {
                    acc[0][f][2] = __builtin_amdgcn_mfma_f32_16x16x32_bf16(ab[cb][f], bb[cb][4], acc[0][f][2], 0, 0, 0);
                    acc[1][f][2] = __builtin_amdgcn_mfma_f32_16x16x32_bf16(ab[cb][f], bb[cb][5], acc[1][f][2], 0, 0, 0);
                }
            }
        }

        // ---- epilogue for this wave's 64 rows x 32 j ----
        #pragma unroll
        for (int jf = 0; jf < 2; ++jf) {
            const int j = jglob + jf * 16 + t;
            const float bgj = b_gd[j];
            const float bdj = b_gd[HID + j];
            const float btj = b_tau[j];
            const float dcj = dconst[j];
            #pragma unroll
            for (int f = 0; f < 4; ++f) {
                #pragma unroll
                for (int r = 0; r < 4; ++r) {
                    const int row = mt * 64 + f * 16 + q * 4 + r;
                    const float gv = acc[jf][f][0][r] + bgj;
                    const float dv = acc[jf][f][1][r] + bdj;
                    const float tp = acc[jf][f][2][r] + btj;
                    const float hv = h_ltc[(size_t)row * HID + j];
                    const float sig = __builtin_amdgcn_rcpf(1.0f + __expf(-gv));
                    const float th  = 1.0f - 2.0f * __builtin_amdgcn_rcpf(__expf(2.0f * dv) + 1.0f);
                    const float tau = fmaxf(tp, 0.0f) + __logf(1.0f + __expf(-fabsf(tp)));
                    out[(size_t)row * HID + j] = (sig * th - hv) * __builtin_amdgcn_rcpf(tau + dcj);
                }
            }
        }
    }
}

// ---------------------------------------------------------------------------
extern "C" void kernel_launch(void* const* d_in, const int* in_sizes, int n_in,
                              void* d_out, int out_size, void* d_ws, size_t ws_size,
                              hipStream_t stream) {
    // setup_inputs order: t, h_ltc, x_t, context, W_gd, b_gd, W_tau, b_tau, gleak, cm
    const float* h_ltc = (const float*)d_in[1];
    const float* x_t   = (const float*)d_in[2];
    const float* ctx   = (const float*)d_in[3];
    const float* W_gd  = (const float*)d_in[4];
    const float* b_gd  = (const float*)d_in[5];
    const float* W_tau = (const float*)d_in[6];
    const float* b_tau = (const float*)d_in[7];
    const float* gleak = (const float*)d_in[8];
    const float* cm    = (const float*)d_in[9];

    char* ws = (char*)d_ws;
    __hip_bfloat16* B_stage = (__hip_bfloat16*)ws;      // 8*112*192*8*2 = 2,752,512 B
    float* dconst = (float*)(ws + 2752512);             // 2,048 B

    pack_B<<<672, 256, 0, stream>>>(W_gd, W_tau, gleak, cm, B_stage, dconst);
    ltc_gemm<<<256, 512, 0, stream>>>(x_t, h_ltc, ctx, B_stage, b_gd, b_tau, dconst,
                                      (float*)d_out);
}